// Round 8
// baseline (9451.582 us; speedup 1.0000x reference)
//
#include <hip/hip_runtime.h>
#include <cstdint>
#include <cstddef>

#define TT 512
#define NWG 256
#define SCH0 32
#define NCH0 16
#define SCH1 16
#define NCH1 32

// ---- Workspace layout (BYTE offsets).
#define OFF_H0   0ul
#define SZ_H0    (512ul*1024ul*64ul*2ul)          /* layer0 out, bf16 (T,1024,B) 64MiB */
#define OFF_OUT  (OFF_H0 + SZ_H0)
#define SZ_OUT   (512ul*512ul*64ul*4ul)           /* l1 fwd+bwd sum fp32; ALSO l0 xw dbuf */
#define OFF_XW1  (OFF_OUT + SZ_OUT)
#define SZ_XW1   (2ul*32ul*2048ul*64ul*4ul)       /* layer1 xw double buffer, 32MiB */
#define OFF_HBUF (OFF_XW1 + SZ_XW1)
#define SZ_HBUF  (2ul*2ul*2ul*512ul*64ul*4ul)     /* [layer][pp][dir] packed-h u32 */
#define OFF_CST  (OFF_HBUF + SZ_HBUF)
#define SZ_CST   (2ul*2ul*512ul*64ul*4ul)         /* unused (layout stability) */
#define OFF_FLG  (OFF_CST + SZ_CST)
#define SZ_FLG   (2ul*2ul*512ul*128ul*4ul)        /* u32 flags [layer][dir][step][slot] */
#define OFF_XWF  (OFF_FLG + SZ_FLG)
#define SZ_XWF   (2ul*2ul*512ul*4ul)              /* u32 counters [layer][dir][step] 0->16 */
#define OFF_SYN  (OFF_XWF + SZ_XWF)
#define SZ_SYN   (256ul)                          /* [0]=l0done, [1]=zcnt */
#define OFF_E    (OFF_SYN + SZ_SYN)
#define SZ_E     (64ul*512ul*4ul)
#define OFF_AT   (OFF_E + SZ_E)
#define SZ_AT    (512ul*64ul*4ul)
#define OFF_POOL (OFF_AT + SZ_AT)
#define SZ_POOL  (512ul*64ul*4ul)

#define SZB0 (2ul*(size_t)SCH0*2048ul*64ul*4ul)   /* 33.5MB l0 xw chunk; 2 fit in SZ_OUT */
#define SZB1 (2ul*(size_t)SCH1*2048ul*64ul*4ul)   /* 16.8MB l1 xw chunk; 2 fit in SZ_XW1 */

#define FUSED_LDS 53248   /* recur 32KB; gemm f32 52.2KB; gemm mfma 40KB; 2 blocks/CU */

typedef unsigned long long u64;
typedef __attribute__((ext_vector_type(8))) short short8v;   // bf16x8 MFMA frag
typedef __attribute__((ext_vector_type(4))) float f32x4;     // MFMA C/D frag

// ALL cross-WG data goes through relaxed agent-scope atomics (sc-flagged ops
// resolve at the device coherence point, bypassing the non-coherent per-XCD
// L2s). Round-7 lesson: plain stores/loads on h0/xw/outsum raced cross-XCD
// inside the single kernel (dispatch boundaries used to hide this).
#define AHL(p)    __hip_atomic_load((p), __ATOMIC_RELAXED, __HIP_MEMORY_SCOPE_AGENT)
#define AHS(p,v)  __hip_atomic_store((p), (v), __ATOMIC_RELAXED, __HIP_MEMORY_SCOPE_AGENT)
#define AFA(p,v)  __hip_atomic_fetch_add((p), (v), __ATOMIC_RELAXED, __HIP_MEMORY_SCOPE_AGENT)

__device__ __forceinline__ unsigned short f2bf(float f) {   // RNE bf16
  unsigned u = __float_as_uint(f);
  u += 0x7fffu + ((u >> 16) & 1u);
  return (unsigned short)(u >> 16);
}

// ---- layer-0 xW GEMM tile (fp32 VALU path; input x fp32, K=256).
__device__ __forceinline__ void gemm_tile_f32(const float* __restrict__ X32,
                                              const float* __restrict__ W,
                                              const float* __restrict__ bias,
                                              float* __restrict__ xwout,
                                              int s0, int sch, int gtile, int sl, int d,
                                              float* Wt, float* Xt) {
  const int K = 256;
  const int tid = threadIdx.x;
  const int sg = s0 + sl;
  const int t = d ? (511 - sg) : sg;
  const int gq = tid >> 4, bq = tid & 15;
  const int g0 = gtile*128 + gq*8;

  float acc[8][4];
  #pragma unroll
  for (int i = 0; i < 8; ++i) {
    const float bv = bias[d*2048 + g0 + i];
    acc[i][0]=bv; acc[i][1]=bv; acc[i][2]=bv; acc[i][3]=bv;
  }
  const float* Wbase = W + ((size_t)d*2048 + gtile*128)*K;

  for (int kc = 0; kc < K; kc += 64) {
    __syncthreads();
    #pragma unroll
    for (int i = 0; i < 8; ++i) {
      const int f4 = i*256 + tid;
      const int row = f4 >> 4, kk4 = (f4 & 15) << 2;
      const int kk4s = kk4 ^ (((row >> 3) & 3) << 2);
      *(float4*)(Wt + row*68 + kk4s) = *(const float4*)(Wbase + (size_t)row*K + kc + kk4);
    }
    {
      const int bb = tid >> 2, kq = tid & 3;
      const float* src = X32 + ((size_t)t*64 + bb)*256 + kc + kq*16;
      #pragma unroll
      for (int i = 0; i < 4; ++i) {
        const float4 v = *(const float4*)(src + i*4);
        const int k = kq*16 + i*4;
        Xt[(k+0)*68 + bb] = v.x;
        Xt[(k+1)*68 + bb] = v.y;
        Xt[(k+2)*68 + bb] = v.z;
        Xt[(k+3)*68 + bb] = v.w;
      }
    }
    __syncthreads();
    for (int k4 = 0; k4 < 64; k4 += 4) {
      float4 w[8];
      #pragma unroll
      for (int i = 0; i < 8; ++i) {
        const int row = gq*8 + i;
        const int k4s = k4 ^ (((row >> 3) & 3) << 2);
        w[i] = *(const float4*)(Wt + row*68 + k4s);
      }
      float4 xv[4];
      #pragma unroll
      for (int kk = 0; kk < 4; ++kk) xv[kk] = *(const float4*)(Xt + (k4+kk)*68 + bq*4);
      #pragma unroll
      for (int i = 0; i < 8; ++i) {
        acc[i][0] += w[i].x*xv[0].x + w[i].y*xv[1].x + w[i].z*xv[2].x + w[i].w*xv[3].x;
        acc[i][1] += w[i].x*xv[0].y + w[i].y*xv[1].y + w[i].z*xv[2].y + w[i].w*xv[3].y;
        acc[i][2] += w[i].x*xv[0].z + w[i].y*xv[1].z + w[i].z*xv[2].z + w[i].w*xv[3].z;
        acc[i][3] += w[i].x*xv[0].w + w[i].y*xv[1].w + w[i].z*xv[2].w + w[i].w*xv[3].w;
      }
    }
  }
  // epilogue: agent-scope atomic dword stores -> visible at coherence point
  float* op = xwout + (((size_t)d*sch + sl)*2048 + g0)*64 + bq*4;
  #pragma unroll
  for (int i = 0; i < 8; ++i) {
    float* p = op + (size_t)i*64;
    AHS(p+0, acc[i][0]); AHS(p+1, acc[i][1]); AHS(p+2, acc[i][2]); AHS(p+3, acc[i][3]);
  }
}

// ---- layer-1 xW GEMM tile (MFMA split-bf16; input h0 bf16, K=1024).
__device__ __forceinline__ void gemm_tile_mfma(const unsigned short* __restrict__ Xb,
                                               const float* __restrict__ W,
                                               const float* __restrict__ bias,
                                               float* __restrict__ xwout,
                                               int s0, int sch, int gtile, int sl, int d,
                                               unsigned short* aWb, unsigned short* aWr,
                                               unsigned short* aX) {
  const int K = 1024;
  const int tid = threadIdx.x;
  const int sg = s0 + sl;
  const int t = d ? (511 - sg) : sg;
  const int w = tid >> 6, lane = tid & 63;
  const int lhi = lane >> 4, lcol = lane & 15;
  const int g0 = gtile*128;
  const float* Wbase = W + ((size_t)d*2048 + g0)*K;
  const unsigned short* Xbase = Xb + (size_t)t*K*64;

  f32x4 acc[8];
  #pragma unroll
  for (int mt = 0; mt < 8; ++mt) acc[mt] = (f32x4){0.f,0.f,0.f,0.f};

  for (int kc = 0; kc < K; kc += 64) {
    __syncthreads();
    #pragma unroll
    for (int i = 0; i < 4; ++i) {
      const int p = i*256 + tid;
      const int row = p >> 3, o = p & 7;
      const float* src = Wbase + (size_t)row*K + kc + o*8;
      const float4 v0 = *(const float4*)(src);
      const float4 v1 = *(const float4*)(src + 4);
      const float f[8] = {v0.x,v0.y,v0.z,v0.w,v1.x,v1.y,v1.z,v1.w};
      short8v vb, vr;
      #pragma unroll
      for (int e = 0; e < 8; ++e) {
        const unsigned short hb = f2bf(f[e]);
        vb[e] = (short)hb;
        vr[e] = (short)f2bf(f[e] - __uint_as_float((unsigned)hb << 16));
      }
      const int os = o ^ (row & 7);
      *(short8v*)(aWb + (size_t)row*64 + os*8) = vb;
      *(short8v*)(aWr + (size_t)row*64 + os*8) = vr;
    }
    // stage X = h0 (written by recurrence WGs via agent atomics -> read the same way)
    #pragma unroll
    for (int i = 0; i < 4; ++i) {
      const int p = i*256 + tid;
      const int k = p >> 4, b4 = (p & 15) << 2;
      const u64 q = AHL((const u64*)(Xbase + (size_t)(kc + k)*64 + b4));
      const unsigned rx = (unsigned)(q & 0xffffffffull);
      const unsigned ry = (unsigned)(q >> 32);
      const int o = k >> 3, e = k & 7;
      aX[((o*64 + b4+0)<<3) + e] = (unsigned short)(rx & 0xffffu);
      aX[((o*64 + b4+1)<<3) + e] = (unsigned short)(rx >> 16);
      aX[((o*64 + b4+2)<<3) + e] = (unsigned short)(ry & 0xffffu);
      aX[((o*64 + b4+3)<<3) + e] = (unsigned short)(ry >> 16);
    }
    __syncthreads();
    #pragma unroll
    for (int ks = 0; ks < 2; ++ks) {
      union { short8v v; } bx;
      bx.v = *(const short8v*)(aX + (((ks*4 + lhi)*64) + w*16 + lcol)*8);
      #pragma unroll
      for (int mt = 0; mt < 8; ++mt) {
        const int row = mt*16 + lcol;
        const int os = (ks*4 + lhi) ^ (row & 7);
        const short8v ab = *(const short8v*)(aWb + (size_t)row*64 + os*8);
        const short8v ar = *(const short8v*)(aWr + (size_t)row*64 + os*8);
        acc[mt] = __builtin_amdgcn_mfma_f32_16x16x32_bf16(ab, bx.v, acc[mt], 0, 0, 0);
        acc[mt] = __builtin_amdgcn_mfma_f32_16x16x32_bf16(ar, bx.v, acc[mt], 0, 0, 0);
      }
    }
  }
  float* op = xwout + (((size_t)d*sch + sl)*2048 + g0)*64 + w*16 + lcol;
  const float* bp = bias + d*2048 + g0;
  #pragma unroll
  for (int mt = 0; mt < 8; ++mt) {
    #pragma unroll
    for (int r = 0; r < 4; ++r) {
      const int grow = mt*16 + lhi*4 + r;
      AHS(op + (size_t)grow*64, acc[mt][r] + bp[grow]);   // agent atomic store
    }
  }
}

// ---- Recurrent layer: gates = Whh16 x h via MFMA split-bf16 (round-6 body).
// Whh staged once per layer; creg in register all layer. xw reads via agent
// atomics (producer writes them atomically from other XCDs).
__device__ __forceinline__ void recur_layer(
    const float* __restrict__ Whh, char* __restrict__ wsb,
    int layer, int SCH, int NCH, float* lds)
{
  unsigned short* alds = (unsigned short*)lds;   // 32KB A-frags (value+residual)

  unsigned short* h0 = (unsigned short*)(wsb + OFF_H0);
  float* outsum  = (float*)(wsb + OFF_OUT);
  unsigned* hbase = (unsigned*)(wsb + OFF_HBUF) + (size_t)layer*131072;
  unsigned* flg  = (unsigned*)(wsb + OFF_FLG);
  unsigned* xwflg= (unsigned*)(wsb + OFF_XWF);
  unsigned* syn  = (unsigned*)(wsb + OFF_SYN);

  const int tid = threadIdx.x;
  const int d     = blockIdx.x >> 7;
  const int slot  = blockIdx.x & 127;
  const int jbase = slot << 2;

  const int w    = tid >> 6;
  const int lane = tid & 63;
  const int lhi  = lane >> 4;
  const int lcol = lane & 15;
  const int jj   = lhi;
  const int b    = w*16 + lcol;

  __builtin_amdgcn_s_setprio(1);

  for (int m = 0; m < 16; ++m) {
    const int g = m & 3, j = m >> 2;
    const float* src = Whh + ((size_t)d*2048 + g*512 + jbase + j)*512;
    for (int k = tid; k < 512; k += 256) {
      const float wv = src[k];
      const unsigned short wb = f2bf(wv);
      const unsigned short wr = f2bf(wv - __uint_as_float((unsigned)wb << 16));
      const int oct = (k >> 3) & 3;
      const int idx = (((k >> 5)*4 + oct)*16 + (m ^ oct))*8 + (k & 7);
      alds[idx] = wb;
      alds[8192 + idx] = wr;
    }
  }
  if (layer == 1 && tid == 0) {   // wait for outsum zeroing
    while (AHL(&syn[1]) < (unsigned)NWG) __builtin_amdgcn_s_sleep(2);
  }
  float creg = 0.0f;
  __syncthreads();

  const unsigned fbase = (unsigned)(layer*2 + d) * 512u;
  unsigned* xwf = xwflg + (size_t)(layer*2 + d)*512;

  for (int c = 0; c < NCH; ++c) {
    const float* xw = (const float*)(wsb + (layer ? OFF_XW1 : OFF_OUT)
                                         + (size_t)(c & 1)*(layer ? SZB1 : SZB0));
    if (tid < SCH) {   // chunk gate: whole chunk's xw produced
      unsigned* p = xwf + c*SCH + tid;
      while (AHL(p) < 16u) __builtin_amdgcn_s_sleep(1);
    }
    __syncthreads();

    for (int sl = 0; sl < SCH; ++sl) {
      const int sg = c*SCH + sl;
      const int t_in = d ? (511 - sg) : sg;

      const float* xwp = xw + ((size_t)(d*SCH + sl)*2048 + (size_t)(jbase + jj))*64 + b;
      const float px0 = AHL(xwp);
      const float px1 = AHL(xwp + 32768);
      const float px2 = AHL(xwp + 65536);
      const float px3 = AHL(xwp + 98304);

      if (sg > 0) {
        if (tid < 128) {
          unsigned* p = &flg[(size_t)(fbase + (unsigned)sg - 1u)*128 + tid];
          while (AHL(p) == 0u) __builtin_amdgcn_s_sleep(1);
        }
        __syncthreads();   // B0
      }

      const u64* hsrc = (const u64*)(hbase + ((sg & 1)*2 + d)*32768);

      u64 ring[8][4];
      #pragma unroll
      for (int ks = 0; ks < 8; ++ks) {
        const size_t hb0 = (size_t)((ks*4 + lhi)*4)*64 + b;
        ring[ks][0] = AHL(hsrc + hb0);
        ring[ks][1] = AHL(hsrc + hb0 + 64);
        ring[ks][2] = AHL(hsrc + hb0 + 128);
        ring[ks][3] = AHL(hsrc + hb0 + 192);
      }

      f32x4 acc = {0.f, 0.f, 0.f, 0.f};
      #pragma unroll
      for (int ks = 0; ks < 16; ++ks) {
        const u64 q0 = ring[ks & 7][0], q1 = ring[ks & 7][1];
        const u64 q2 = ring[ks & 7][2], q3 = ring[ks & 7][3];
        if (ks < 8) {
          const size_t hb2 = (size_t)(((ks + 8)*4 + lhi)*4)*64 + b;
          ring[ks][0] = AHL(hsrc + hb2);
          ring[ks][1] = AHL(hsrc + hb2 + 64);
          ring[ks][2] = AHL(hsrc + hb2 + 128);
          ring[ks][3] = AHL(hsrc + hb2 + 192);
        }
        union { unsigned u[4]; short8v v; } hb, rb;
        hb.u[0] = __builtin_amdgcn_perm((unsigned)(q0 >> 32), (unsigned)q0, 0x07060302u);
        rb.u[0] = __builtin_amdgcn_perm((unsigned)(q0 >> 32), (unsigned)q0, 0x05040100u);
        hb.u[1] = __builtin_amdgcn_perm((unsigned)(q1 >> 32), (unsigned)q1, 0x07060302u);
        rb.u[1] = __builtin_amdgcn_perm((unsigned)(q1 >> 32), (unsigned)q1, 0x05040100u);
        hb.u[2] = __builtin_amdgcn_perm((unsigned)(q2 >> 32), (unsigned)q2, 0x07060302u);
        rb.u[2] = __builtin_amdgcn_perm((unsigned)(q2 >> 32), (unsigned)q2, 0x05040100u);
        hb.u[3] = __builtin_amdgcn_perm((unsigned)(q3 >> 32), (unsigned)q3, 0x07060302u);
        rb.u[3] = __builtin_amdgcn_perm((unsigned)(q3 >> 32), (unsigned)q3, 0x05040100u);
        const int abase = ((ks*4 + lhi)*16 + (lcol ^ lhi))*8;
        const short8v ab = *(const short8v*)(alds + abase);
        const short8v ar = *(const short8v*)(alds + 8192 + abase);
        acc = __builtin_amdgcn_mfma_f32_16x16x32_bf16(ab, hb.v, acc, 0, 0, 0);
        acc = __builtin_amdgcn_mfma_f32_16x16x32_bf16(ab, rb.v, acc, 0, 0, 0);
        acc = __builtin_amdgcn_mfma_f32_16x16x32_bf16(ar, hb.v, acc, 0, 0, 0);
      }

      const float pi = acc[0] + px0;
      const float pf = acc[1] + px1;
      const float pg = acc[2] + px2;
      const float po = acc[3] + px3;
      const float iv = 1.0f/(1.0f + __expf(-pi));
      const float fv = 1.0f/(1.0f + __expf(-pf));
      const float gv = tanhf(pg);
      const float ov = 1.0f/(1.0f + __expf(-po));
      float cc2 = fv*creg + iv*gv;
      cc2 = fminf(fmaxf(cc2, -100.0f), 100.0f);
      creg = cc2;
      const float h = ov*tanhf(cc2);

      const unsigned short hb16 = f2bf(h);
      const unsigned short rb16 = f2bf(h - __uint_as_float((unsigned)hb16 << 16));
      const unsigned hpk = ((unsigned)hb16 << 16) | (unsigned)rb16;
      unsigned* hout = hbase + (((sg & 1) ^ 1)*2 + d)*32768;
      const int kj = jbase + jj;
      AHS(hout + ((size_t)(kj >> 1)*128 + b*2 + (kj & 1)), hpk);

      __syncthreads();   // Bend: drains each wave's vmcnt -> h stores ACKed
      if (tid == 0)
        AHS(&flg[(size_t)(fbase + (unsigned)sg)*128 + slot], 1u);
      // deferred outputs (cross-XCD consumers) -> agent atomics too:
      if (layer == 0) {
        // pack two adjacent-b bf16s into one u32 agent atomic store
        const unsigned other = __shfl_xor((unsigned)hb16, 1);
        if ((b & 1) == 0) {
          const unsigned pk = (unsigned)hb16 | (other << 16);
          unsigned* hp = (unsigned*)(h0 + (size_t)t_in*65536 + (size_t)(d*512 + kj)*64 + b);
          AHS(hp, pk);
        }
      } else {
        atomicAdd(&outsum[(size_t)t_in*32768 + (size_t)kj*64 + b], h);
      }
    }
  }
}

// ---- Mega kernel: blocks 0..255 recurrence (l0 then l1); blocks 256..511
// persistent GEMM workers, flag-paced. 512 WGs = 256 CU x 2 co-resident
// (LDS 2x52KB <= 160KB, launch_bounds(256,2)); dependency DAG acyclic.
__global__ void __launch_bounds__(256, 2) mega(
    const float* __restrict__ x,
    const float* __restrict__ Wih0, const float* __restrict__ Whh0, const float* __restrict__ b0,
    const float* __restrict__ Wih1, const float* __restrict__ Whh1, const float* __restrict__ b1,
    char* __restrict__ wsb)
{
  extern __shared__ float lds[];
  const int tid = threadIdx.x;
  unsigned* flg   = (unsigned*)(wsb + OFF_FLG);
  unsigned* xwflg = (unsigned*)(wsb + OFF_XWF);
  unsigned* syn   = (unsigned*)(wsb + OFF_SYN);

  if (blockIdx.x < NWG) {
    // -------- recurrence role --------
    recur_layer(Whh0, wsb, 0, SCH0, NCH0, lds);
    __syncthreads();   // drains vmcnt incl. final deferred h0 atomic store
    if (tid == 0) AFA(&syn[0], 1u);            // l0done
    recur_layer(Whh1, wsb, 1, SCH1, NCH1, lds);
  } else {
    // -------- gemm role --------
    const int wg = blockIdx.x - NWG;
    // layer 0: f32 path, 1024 jobs/chunk -> 4 jobs/WG, all same (d, sl)
    {
      const int sl = wg >> 3, jd = (wg >> 2) & 1, gt0 = (wg & 3) * 4;
      for (int c = 0; c < NCH0; ++c) {
        if (c >= 2) {   // anti-overwrite: recurrence done with chunk c-2 (same parity)
          const unsigned gate = (unsigned)((c - 1)*SCH0 - 1);
          if (tid < 128) {
            unsigned* p = &flg[(size_t)((unsigned)(0*2 + jd)*512u + gate)*128 + tid];
            while (AHL(p) == 0u) __builtin_amdgcn_s_sleep(1);
          }
          __syncthreads();
        }
        float* xw = (float*)(wsb + OFF_OUT + (size_t)(c & 1)*SZB0);
        #pragma unroll 1
        for (int i = 0; i < 4; ++i)
          gemm_tile_f32(x, Wih0, b0, xw, c*SCH0, SCH0, gt0 + i, sl, jd, lds, lds + 128*68);
        __syncthreads();   // drains all waves' xw atomic stores (ACKed at fabric)
        if (tid == 0) AFA(&xwflg[(size_t)(0*2 + jd)*512 + c*SCH0 + sl], 4u);
      }
    }
    // wait recurrence l0 fully done (h0 atomic stores all ACKed before syn[0])
    if (tid == 0) { while (AHL(&syn[0]) < (unsigned)NWG) __builtin_amdgcn_s_sleep(2); }
    __syncthreads();
    // zero my outsum slice via agent atomic stores (cross-XCD consumers: atomicAdd)
    {
      unsigned* dst = (unsigned*)(wsb + OFF_OUT) + (size_t)wg*65536 + tid;
      #pragma unroll 4
      for (int i = 0; i < 256; ++i) AHS(dst + (size_t)i*256, 0u);
    }
    __syncthreads();   // drains zero stores
    if (tid == 0) AFA(&syn[1], 1u);            // zcnt
    // layer 1: MFMA path, 512 jobs/chunk -> 2 jobs/WG, all same (d, sl)
    {
      const unsigned short* h0p = (const unsigned short*)(wsb + OFF_H0);
      unsigned short* aWb = (unsigned short*)lds;
      unsigned short* aWr = aWb + 8192;
      unsigned short* aX  = aWr + 8192;
      const int sl = wg >> 4, jd = (wg >> 3) & 1, gt0 = (wg & 7) * 2;
      for (int c = 0; c < NCH1; ++c) {
        if (c >= 2) {
          const unsigned gate = (unsigned)((c - 1)*SCH1 - 1);
          if (tid < 128) {
            unsigned* p = &flg[(size_t)((unsigned)(2 + jd)*512u + gate)*128 + tid];
            while (AHL(p) == 0u) __builtin_amdgcn_s_sleep(1);
          }
          __syncthreads();
        }
        float* xw = (float*)(wsb + OFF_XW1 + (size_t)(c & 1)*SZB1);
        #pragma unroll 1
        for (int i = 0; i < 2; ++i)
          gemm_tile_mfma(h0p, Wih1, b1, xw, c*SCH1, SCH1, gt0 + i, sl, jd, aWb, aWr, aX);
        __syncthreads();   // drains xw atomic stores
        if (tid == 0) AFA(&xwflg[(size_t)(2 + jd)*512 + c*SCH1 + sl], 2u);
      }
    }
  }
}

// ---- attention / output chain (unchanged; separate dispatches -> coherent) ----
__global__ void __launch_bounds__(256) attn_logits(const float* __restrict__ outsum,
                                                   const float* __restrict__ Wa,
                                                   const float* __restrict__ ba,
                                                   float* __restrict__ e) {
  __shared__ float part[4*64];
  const int t = blockIdx.x;
  const int b = threadIdx.x & 63, jq = threadIdx.x >> 6;
  const float* base = outsum + (size_t)t * 512 * 64;
  float acc = 0.0f;
  for (int j = jq*128; j < jq*128 + 128; ++j)
    acc += base[j*64 + b] * Wa[j];
  part[jq*64 + b] = acc;
  __syncthreads();
  if (threadIdx.x < 64) {
    const int bb = threadIdx.x;
    e[bb*512 + t] = part[0*64+bb] + part[1*64+bb] + part[2*64+bb] + part[3*64+bb] + ba[0];
  }
}

__global__ void __launch_bounds__(256) attn_softmax(const float* __restrict__ e,
                                                    float* __restrict__ attn,
                                                    float* __restrict__ aT) {
  __shared__ float red[256];
  const int b = blockIdx.x, tid = threadIdx.x;
  const float v0 = e[b*512 + tid];
  const float v1 = e[b*512 + 256 + tid];
  red[tid] = fmaxf(v0, v1);
  __syncthreads();
  for (int st = 128; st; st >>= 1) { if (tid < st) red[tid] = fmaxf(red[tid], red[tid+st]); __syncthreads(); }
  const float M = red[0];
  __syncthreads();
  const float e0 = __expf(v0 - M), e1 = __expf(v1 - M);
  red[tid] = e0 + e1;
  __syncthreads();
  for (int st = 128; st; st >>= 1) { if (tid < st) red[tid] += red[tid+st]; __syncthreads(); }
  const float inv = 1.0f / red[0];
  const float a0 = e0*inv, a1 = e1*inv;
  attn[b*512 + tid]       = a0;
  attn[b*512 + 256 + tid] = a1;
  aT[tid*64 + b]       = a0;
  aT[(256+tid)*64 + b] = a1;
}

__global__ void __launch_bounds__(256) attn_pool(const float* __restrict__ outsum,
                                                 const float* __restrict__ aT,
                                                 float* __restrict__ pooled) {
  const int tid = threadIdx.x;
  const int b = tid & 63, jj = tid >> 6;
  const int j = blockIdx.x*4 + jj;
  float acc = 0.0f;
  #pragma unroll 4
  for (int t = 0; t < 512; ++t)
    acc += aT[t*64 + b] * outsum[((size_t)t*512 + j)*64 + b];
  pooled[j*64 + b] = acc;
}

__global__ void __launch_bounds__(128) pred_kern(const float* __restrict__ pooled,
                                                 const float* __restrict__ Wo,
                                                 const float* __restrict__ bo,
                                                 float* __restrict__ out) {
  const int b = blockIdx.x, o = threadIdx.x;
  float acc = bo[o];
  const float* wr = Wo + o*512;
  #pragma unroll 4
  for (int j = 0; j < 512; j += 4) {
    const float4 w = *(const float4*)(wr + j);
    acc += w.x*pooled[(j+0)*64 + b] + w.y*pooled[(j+1)*64 + b]
         + w.z*pooled[(j+2)*64 + b] + w.w*pooled[(j+3)*64 + b];
  }
  out[b*128 + o] = acc;
}

extern "C" void kernel_launch(void* const* d_in, const int* in_sizes, int n_in,
                              void* d_out, int out_size, void* d_ws, size_t ws_size,
                              hipStream_t stream) {
  (void)in_sizes; (void)n_in; (void)out_size; (void)ws_size;
  const float* x    = (const float*)d_in[0];
  const float* Wih0 = (const float*)d_in[1];
  const float* Whh0 = (const float*)d_in[2];
  const float* b0   = (const float*)d_in[3];
  const float* Wih1 = (const float*)d_in[4];
  const float* Whh1 = (const float*)d_in[5];
  const float* b1   = (const float*)d_in[6];
  const float* Wa   = (const float*)d_in[7];
  const float* ba   = (const float*)d_in[8];
  const float* Wo   = (const float*)d_in[9];
  const float* bo   = (const float*)d_in[10];
  float* out = (float*)d_out;
  char* wsb  = (char*)d_ws;

  // zero hbuf + cstore + flags + xwflg + syn (contiguous) — per-launch reset
  hipMemsetAsync(wsb + OFF_HBUF, 0, SZ_HBUF + SZ_CST + SZ_FLG + SZ_XWF + SZ_SYN, stream);

  mega<<<dim3(2*NWG), dim3(256), FUSED_LDS, stream>>>(x, Wih0, Whh0, b0, Wih1, Whh1, b1, wsb);

  attn_logits <<<512, 256, 0, stream>>>((float*)(wsb + OFF_OUT), Wa, ba, (float*)(wsb + OFF_E));
  attn_softmax<<< 64, 256, 0, stream>>>((float*)(wsb + OFF_E), out + 8192, (float*)(wsb + OFF_AT));
  attn_pool   <<<128, 256, 0, stream>>>((float*)(wsb + OFF_OUT), (float*)(wsb + OFF_AT),
                                        (float*)(wsb + OFF_POOL));
  pred_kern   <<< 64, 128, 0, stream>>>((float*)(wsb + OFF_POOL), Wo, bo, out);
}